// Round 18
// baseline (106.604 us; speedup 1.0000x reference)
//
#include <hip/hip_runtime.h>

// Shapes fixed by the reference: N=M=512, B=1, C=256, H=8, Dh=32, fp32.

// DPP-based add-exchange (pure VALU, avoids ds_swizzle / LDS pipe).
template <int CTRL, int RMASK>
__device__ __forceinline__ float dpp_add(float v) {
  int x = __builtin_amdgcn_update_dpp(0, __float_as_int(v), CTRL, RMASK, 0xf, false);
  return v + __int_as_float(x);
}

// ---------------- Kernel 1: projections q,k,v = x @ W^T + b (in-kernel transpose) ----------------
__global__ __launch_bounds__(256) void k_proj(const float* __restrict__ q_in,
                                              const float* __restrict__ k_in,
                                              const float* __restrict__ v_in,
                                              const float* __restrict__ bq,
                                              const float* __restrict__ bk,
                                              const float* __restrict__ bv,
                                              const float* __restrict__ Wq,
                                              const float* __restrict__ Wk,
                                              const float* __restrict__ Wv,
                                              float* __restrict__ outb) {
  const int mat = blockIdx.y;
  const float* x = mat == 0 ? q_in : mat == 1 ? k_in : v_in;
  const float* b = mat == 0 ? bq : mat == 1 ? bk : bv;
  const float* W = mat == 0 ? Wq : mat == 1 ? Wk : Wv;
  float* out = outb + (size_t)mat * 131072;

  __shared__ float xl[8][256];
  __shared__ float wtile[256][33];  // +1 pad: column reads conflict-free
  const int tid = threadIdx.x;
  const int n0 = blockIdx.x * 8;
  for (int idx = tid; idx < 2048; idx += 256)
    xl[idx >> 8][idx & 255] = x[(n0 + (idx >> 8)) * 256 + (idx & 255)];

  float acc[8] = {0.f, 0.f, 0.f, 0.f, 0.f, 0.f, 0.f, 0.f};
  for (int j0 = 0; j0 < 256; j0 += 32) {
    __syncthreads();  // first iter: xl ready; later: wtile readers done
    for (int idx = tid; idx < 8192; idx += 256) {
      const int cc = idx >> 5, jj = idx & 31;
      wtile[cc][jj] = W[cc * 256 + j0 + jj];
    }
    __syncthreads();
#pragma unroll
    for (int jj = 0; jj < 32; jj += 4) {
      const float w0 = wtile[tid][jj + 0];
      const float w1 = wtile[tid][jj + 1];
      const float w2 = wtile[tid][jj + 2];
      const float w3 = wtile[tid][jj + 3];
#pragma unroll
      for (int r = 0; r < 8; ++r) {
        const float4 xv = *(const float4*)&xl[r][j0 + jj];
        acc[r] += xv.x * w0 + xv.y * w1 + xv.z * w2 + xv.w * w3;
      }
    }
  }
  const float bb = b[tid];
#pragma unroll
  for (int r = 0; r < 8; ++r) out[(n0 + r) * 256 + tid] = acc[r] + bb;
}

// ---------------- Kernel 2: FUSED t-fold + scores + softmax + attn + attn@v ----------------
// One block per n, 256 threads = 4 waves, 4 blocks/CU (same 16 waves/CU as the
// 512-thread version, but 4 independent blocks per CU let the scheduler overlap
// one block's epilogue (softmax/attn/PV) with another's E-stream — the 512-thread
// 2-block/CU version serialized that ~15-20us tail).
// Stream: wave w owns m-rows [w*128, (w+1)*128), 2 rows/iter (one per 32-lane
// half); 32 lanes/row, 8 ch/lane; t fragment 64 regs; K folded via select
// trick; 5-step DPP reduce; cndmask gather; single predicated store. PLAIN
// loads (R16: nontemporal hurt). Softmax: wave w = heads 2w,2w+1. PV: float4
// v-loads, 4 m-chunks of 128.
__global__ __launch_bounds__(256, 4) void k_main(const float* __restrict__ Eg,
                                                 const float* __restrict__ qkv,
                                                 const float* __restrict__ Wg,
                                                 float* __restrict__ out) {
  const float* k_g = qkv + 131072;
  const float* v_g = qkv + 262144;
  const int n = blockIdx.x;
  const int tid = threadIdx.x;
  const int lane = tid & 63, w = tid >> 6;
  const int s = lane & 31, g = lane >> 5;
  const int hd = s >> 2;  // head owning this lane's 8 channels
  const float scale = 0.17677669529663687f;  // 1/sqrt(32)
  float* attn = out + 131072;

  __shared__ float ql[256];       // q[n]
  __shared__ float t_lds[2048];   // [8 heads][256 j], pre-scaled
  __shared__ float sc[8 * 520];   // [8 heads][520 stride] raw-then-exp scores
  __shared__ float invd[8];
  __shared__ float pv2[4 * 260];  // padded partial PV sums (4 m-chunks)

  // ---- prologue: q -> LDS, then t-fold into t_lds ----
  ql[tid] = qkv[n * 256 + tid];
  __syncthreads();
  {
    const int jcol = tid;  // thread = column j, all 8 heads
#pragma unroll
    for (int h = 0; h < 8; ++h) {
      float a = 0.f;
      const float* wg = Wg + (size_t)(h * 32) * 256 + jcol;
#pragma unroll 8
      for (int i = 0; i < 32; ++i) a = fmaf(ql[h * 32 + i], wg[(size_t)i * 256], a);
      t_lds[h * 256 + jcol] = a * scale;
    }
  }
  __syncthreads();

  // t fragment: 8 heads x this lane's 8 channels
  float t_r[8][8];
#pragma unroll
  for (int h = 0; h < 8; ++h) {
#pragma unroll
    for (int c = 0; c < 8; ++c) t_r[h][c] = t_lds[h * 256 + s * 8 + c];
  }
  // q fragment, pre-scaled (so kacc lands scaled)
  float q_r[8];
#pragma unroll
  for (int c = 0; c < 8; ++c) q_r[c] = ql[s * 8 + c] * scale;

  // ---- stream phase: wave w rows [w*128, w*128+128), 2 rows/iter ----
  const float* E0 = Eg + ((size_t)n * 512 + w * 128 + g) * 256 + s * 8;
  const float* K0 = k_g + (size_t)(w * 128 + g) * 256 + s * 8;

#pragma unroll 4
  for (int it = 0; it < 64; ++it) {
    const float4 e0 = *(const float4*)(E0);
    const float4 e1 = *(const float4*)(E0 + 4);
    const float4 k0 = *(const float4*)(K0);
    const float4 k1 = *(const float4*)(K0 + 4);
    // k-dot partial: this lane's channels all belong to head hd
    float kacc;
    kacc = k0.x * q_r[0];             kacc = fmaf(k0.y, q_r[1], kacc);
    kacc = fmaf(k0.z, q_r[2], kacc);  kacc = fmaf(k0.w, q_r[3], kacc);
    kacc = fmaf(k1.x, q_r[4], kacc);  kacc = fmaf(k1.y, q_r[5], kacc);
    kacc = fmaf(k1.z, q_r[6], kacc);  kacc = fmaf(k1.w, q_r[7], kacc);
    const int m = w * 128 + it * 2 + g;
    float vout = 0.f;
#pragma unroll
    for (int h = 0; h < 8; ++h) {
      float v = (hd == h) ? kacc : 0.f;   // loop-invariant mask -> cndmask
      v = fmaf(e0.x, t_r[h][0], v); v = fmaf(e0.y, t_r[h][1], v);
      v = fmaf(e0.z, t_r[h][2], v); v = fmaf(e0.w, t_r[h][3], v);
      v = fmaf(e1.x, t_r[h][4], v); v = fmaf(e1.y, t_r[h][5], v);
      v = fmaf(e1.z, t_r[h][6], v); v = fmaf(e1.w, t_r[h][7], v);
      // 32-lane reduce: xor1, xor2, half_mirror(xor4), mirror(xor8),
      // bcast15 folds row0 into row1 (valid in lanes 16-31 / 48-63).
      v = dpp_add<0xB1, 0xf>(v);
      v = dpp_add<0x4E, 0xf>(v);
      v = dpp_add<0x141, 0xf>(v);
      v = dpp_add<0x140, 0xf>(v);
      v = dpp_add<0x142, 0xa>(v);
      vout = (s == 16 + h) ? v : vout;    // loop-invariant mask -> cndmask
    }
    // single predicated store: lanes 16-23 (row m, g=0) and 48-55 (row m+1, g=1)
    if ((unsigned)(s - 16) < 8u) sc[(s - 16) * 520 + m] = vout;
    E0 += 512; K0 += 512;
  }
  __syncthreads();

  // ---- softmax over m: wave w handles heads 2w, 2w+1 ----
#pragma unroll
  for (int hh = 0; hh < 2; ++hh) {
    const int h = w * 2 + hh;
    float vals[8];
#pragma unroll
    for (int i = 0; i < 8; ++i) vals[i] = sc[h * 520 + lane + i * 64];
    float mx = vals[0];
#pragma unroll
    for (int i = 1; i < 8; ++i) mx = fmaxf(mx, vals[i]);
#pragma unroll
    for (int off = 1; off < 64; off <<= 1) mx = fmaxf(mx, __shfl_xor(mx, off));
    float sum = 0.f;
#pragma unroll
    for (int i = 0; i < 8; ++i) {
      const float e = __expf(vals[i] - mx);
      sum += e;
      sc[h * 520 + lane + i * 64] = e;
    }
#pragma unroll
    for (int off = 1; off < 64; off <<= 1) sum += __shfl_xor(sum, off);
    if (lane == 0) invd[h] = 1.f / sum;
  }
  __syncthreads();

  // ---- normalized attn write (4096 values, 16 per thread) ----
#pragma unroll
  for (int r = 0; r < 16; ++r) {
    const int idx = tid + r * 256;
    const int h = idx >> 9, mm = idx & 511;
    attn[(size_t)h * 262144 + n * 512 + mm] = sc[h * 520 + mm] * invd[h];
  }

  // ---- PV: thread covers c4..c4+3 (float4 v loads), m-chunk mc of 128 rows ----
  {
    const int c4 = (tid & 63) * 4;       // 0..252
    const int mc = tid >> 6;             // 0..3 (uniform per wave)
    const int hh = (tid & 63) >> 3;      // head of c4..c4+3
    const float* pr = sc + hh * 520 + mc * 128;
    const float* vp = v_g + (size_t)(mc * 128) * 256 + c4;
    float4 a4 = {0.f, 0.f, 0.f, 0.f};
#pragma unroll 4
    for (int m = 0; m < 128; ++m) {
      const float p = pr[m];
      const float4 v4 = *(const float4*)vp;
      a4.x = fmaf(p, v4.x, a4.x);
      a4.y = fmaf(p, v4.y, a4.y);
      a4.z = fmaf(p, v4.z, a4.z);
      a4.w = fmaf(p, v4.w, a4.w);
      vp += 256;
    }
    *(float4*)&pv2[mc * 260 + c4] = a4;
  }
  __syncthreads();
  {
    float acc = 0.f;
#pragma unroll
    for (int mc2 = 0; mc2 < 4; ++mc2) acc += pv2[mc2 * 260 + tid];
    out[n * 256 + tid] = acc * invd[tid >> 5];
  }
}

extern "C" void kernel_launch(void* const* d_in, const int* in_sizes, int n_in,
                              void* d_out, int out_size, void* d_ws, size_t ws_size,
                              hipStream_t stream) {
  const float* query = (const float*)d_in[0];
  const float* key   = (const float*)d_in[1];
  const float* value = (const float*)d_in[2];
  const float* Eg    = (const float*)d_in[3];
  const float* Wq    = (const float*)d_in[4];
  const float* bq    = (const float*)d_in[5];
  const float* Wk    = (const float*)d_in[6];
  const float* bk    = (const float*)d_in[7];
  const float* Wv    = (const float*)d_in[8];
  const float* bv    = (const float*)d_in[9];
  const float* Wg    = (const float*)d_in[10];
  float* out = (float*)d_out;

  // ws layout (floats): qkv[3*131072]  = 1.5 MB
  float* qkv = (float*)d_ws;

  k_proj<<<dim3(64, 3), 256, 0, stream>>>(query, key, value, bq, bk, bv, Wq, Wk, Wv, qkv);
  k_main<<<dim3(512), 256, 0, stream>>>(Eg, qkv, Wg, out);
}

// Round 19
// 97.656 us; speedup vs baseline: 1.0916x; 1.0916x over previous
//
#include <hip/hip_runtime.h>

// Shapes fixed by the reference: N=M=512, B=1, C=256, H=8, Dh=32, fp32.

// DPP-based add-exchange (pure VALU, avoids ds_swizzle / LDS pipe).
template <int CTRL, int RMASK>
__device__ __forceinline__ float dpp_add(float v) {
  int x = __builtin_amdgcn_update_dpp(0, __float_as_int(v), CTRL, RMASK, 0xf, false);
  return v + __int_as_float(x);
}

// ---------------- Kernel 1: projections q,k,v = x @ W^T + b (in-kernel transpose) ----------------
// Stages W[0:256][j0:j0+32] tiles in LDS (coalesced row reads, +1 pad ->
// conflict-free column access).
__global__ __launch_bounds__(256) void k_proj(const float* __restrict__ q_in,
                                              const float* __restrict__ k_in,
                                              const float* __restrict__ v_in,
                                              const float* __restrict__ bq,
                                              const float* __restrict__ bk,
                                              const float* __restrict__ bv,
                                              const float* __restrict__ Wq,
                                              const float* __restrict__ Wk,
                                              const float* __restrict__ Wv,
                                              float* __restrict__ outb) {
  const int mat = blockIdx.y;
  const float* x = mat == 0 ? q_in : mat == 1 ? k_in : v_in;
  const float* b = mat == 0 ? bq : mat == 1 ? bk : bv;
  const float* W = mat == 0 ? Wq : mat == 1 ? Wk : Wv;
  float* out = outb + (size_t)mat * 131072;

  __shared__ float xl[8][256];
  __shared__ float wtile[256][33];  // +1 pad: column reads conflict-free
  const int tid = threadIdx.x;
  const int n0 = blockIdx.x * 8;
  for (int idx = tid; idx < 2048; idx += 256)
    xl[idx >> 8][idx & 255] = x[(n0 + (idx >> 8)) * 256 + (idx & 255)];

  float acc[8] = {0.f, 0.f, 0.f, 0.f, 0.f, 0.f, 0.f, 0.f};
  for (int j0 = 0; j0 < 256; j0 += 32) {
    __syncthreads();  // first iter: xl ready; later: wtile readers done
    for (int idx = tid; idx < 8192; idx += 256) {
      const int cc = idx >> 5, jj = idx & 31;
      wtile[cc][jj] = W[cc * 256 + j0 + jj];
    }
    __syncthreads();
#pragma unroll
    for (int jj = 0; jj < 32; jj += 4) {
      const float w0 = wtile[tid][jj + 0];
      const float w1 = wtile[tid][jj + 1];
      const float w2 = wtile[tid][jj + 2];
      const float w3 = wtile[tid][jj + 3];
#pragma unroll
      for (int r = 0; r < 8; ++r) {
        const float4 xv = *(const float4*)&xl[r][j0 + jj];
        acc[r] += xv.x * w0 + xv.y * w1 + xv.z * w2 + xv.w * w3;
      }
    }
  }
  const float bb = b[tid];
#pragma unroll
  for (int r = 0; r < 8; ++r) out[(n0 + r) * 256 + tid] = acc[r] + bb;
}

// ---------------- Kernel 2: FUSED t-fold + scores + softmax + attn + attn@v ----------------
// One block per n, 512 threads = 8 waves, 2 blocks/CU (measured best — R18's
// 256-thread/4-block variant regressed 11us).
// Prologue: t[n][h][j] = sum_i q[n,i]*Wg[i,j] (pre-scaled) in-block into LDS;
//   qb dropped (softmax shift-invariance).
// Stream (R10 structure): wave w owns m-rows [w*64, w*64+64), 2 rows/iter;
//   32 lanes/row, 8 ch/lane; t fragment 64 regs; K folded via select trick;
//   5-step DPP reduce; cndmask gather; single predicated store. PLAIN loads
//   (R16: nontemporal hurt — L3 assist matters).
// Epilogue: softmax per head per wave; attn write; PV float4 v-loads.
__global__ __launch_bounds__(512, 4) void k_main(const float* __restrict__ Eg,
                                                 const float* __restrict__ qkv,
                                                 const float* __restrict__ Wg,
                                                 float* __restrict__ out) {
  const float* k_g = qkv + 131072;
  const float* v_g = qkv + 262144;
  const int n = blockIdx.x;
  const int tid = threadIdx.x;
  const int lane = tid & 63, w = tid >> 6;
  const int s = lane & 31, g = lane >> 5;
  const int hd = s >> 2;  // head owning this lane's 8 channels
  const float scale = 0.17677669529663687f;  // 1/sqrt(32)
  float* attn = out + 131072;

  __shared__ float ql[256];       // q[n]
  __shared__ float t_lds[2048];   // [8 heads][256 j], pre-scaled
  __shared__ float sc[8 * 520];   // [8 heads][520 stride] raw-then-exp scores
  __shared__ float invd[8];
  __shared__ float pv2[8 * 260];  // padded partial PV sums

  // ---- prologue: q -> LDS, then t-fold into t_lds ----
  if (tid < 256) ql[tid] = qkv[n * 256 + tid];
  __syncthreads();
  {
    const int jcol = tid & 255, hb = (tid >> 8) * 4;  // thread: col j, 4 heads
#pragma unroll
    for (int hh = 0; hh < 4; ++hh) {
      const int h = hb + hh;
      float a = 0.f;
      const float* wg = Wg + (size_t)(h * 32) * 256 + jcol;
#pragma unroll 8
      for (int i = 0; i < 32; ++i) a = fmaf(ql[h * 32 + i], wg[(size_t)i * 256], a);
      t_lds[h * 256 + jcol] = a * scale;
    }
  }
  __syncthreads();

  // t fragment: 8 heads x this lane's 8 channels
  float t_r[8][8];
#pragma unroll
  for (int h = 0; h < 8; ++h) {
#pragma unroll
    for (int c = 0; c < 8; ++c) t_r[h][c] = t_lds[h * 256 + s * 8 + c];
  }
  // q fragment, pre-scaled (so kacc lands scaled)
  float q_r[8];
#pragma unroll
  for (int c = 0; c < 8; ++c) q_r[c] = ql[s * 8 + c] * scale;

  // ---- stream phase: rows w*64 + it*2 + g ----
  const float* E0 = Eg + ((size_t)n * 512 + w * 64 + g) * 256 + s * 8;
  const float* K0 = k_g + (size_t)(w * 64 + g) * 256 + s * 8;

#pragma unroll 4
  for (int it = 0; it < 32; ++it) {
    const float4 e0 = *(const float4*)(E0);
    const float4 e1 = *(const float4*)(E0 + 4);
    const float4 k0 = *(const float4*)(K0);
    const float4 k1 = *(const float4*)(K0 + 4);
    // k-dot partial: this lane's channels all belong to head hd
    float kacc;
    kacc = k0.x * q_r[0];             kacc = fmaf(k0.y, q_r[1], kacc);
    kacc = fmaf(k0.z, q_r[2], kacc);  kacc = fmaf(k0.w, q_r[3], kacc);
    kacc = fmaf(k1.x, q_r[4], kacc);  kacc = fmaf(k1.y, q_r[5], kacc);
    kacc = fmaf(k1.z, q_r[6], kacc);  kacc = fmaf(k1.w, q_r[7], kacc);
    const int m = w * 64 + it * 2 + g;
    float vout = 0.f;
#pragma unroll
    for (int h = 0; h < 8; ++h) {
      float v = (hd == h) ? kacc : 0.f;   // loop-invariant mask -> cndmask
      v = fmaf(e0.x, t_r[h][0], v); v = fmaf(e0.y, t_r[h][1], v);
      v = fmaf(e0.z, t_r[h][2], v); v = fmaf(e0.w, t_r[h][3], v);
      v = fmaf(e1.x, t_r[h][4], v); v = fmaf(e1.y, t_r[h][5], v);
      v = fmaf(e1.z, t_r[h][6], v); v = fmaf(e1.w, t_r[h][7], v);
      // 32-lane reduce: xor1, xor2, half_mirror(xor4), mirror(xor8),
      // bcast15 folds row0 into row1 (valid in lanes 16-31 / 48-63).
      v = dpp_add<0xB1, 0xf>(v);
      v = dpp_add<0x4E, 0xf>(v);
      v = dpp_add<0x141, 0xf>(v);
      v = dpp_add<0x140, 0xf>(v);
      v = dpp_add<0x142, 0xa>(v);
      vout = (s == 16 + h) ? v : vout;    // loop-invariant mask -> cndmask
    }
    // single predicated store: lanes 16-23 (row m, g=0) and 48-55 (row m+1, g=1)
    if ((unsigned)(s - 16) < 8u) sc[(s - 16) * 520 + m] = vout;
    E0 += 512; K0 += 512;
  }
  __syncthreads();

  // ---- softmax over m for head w ----
  {
    float vals[8];
#pragma unroll
    for (int i = 0; i < 8; ++i) vals[i] = sc[w * 520 + lane + i * 64];
    float mx = vals[0];
#pragma unroll
    for (int i = 1; i < 8; ++i) mx = fmaxf(mx, vals[i]);
#pragma unroll
    for (int off = 1; off < 64; off <<= 1) mx = fmaxf(mx, __shfl_xor(mx, off));
    float sum = 0.f;
#pragma unroll
    for (int i = 0; i < 8; ++i) {
      const float e = __expf(vals[i] - mx);
      sum += e;
      sc[w * 520 + lane + i * 64] = e;
    }
#pragma unroll
    for (int off = 1; off < 64; off <<= 1) sum += __shfl_xor(sum, off);
    if (lane == 0) invd[w] = 1.f / sum;
  }
  __syncthreads();

  // ---- normalized attn write ----
#pragma unroll
  for (int r = 0; r < 8; ++r) {
    const int idx = tid + r * 512;
    const int h = idx >> 9, mm = idx & 511;
    attn[(size_t)h * 262144 + n * 512 + mm] = sc[h * 520 + mm] * invd[h];
  }

  // ---- PV: thread covers c4..c4+3 (float4 v loads), m-chunk mc of 64 rows ----
  {
    const int c4 = (tid & 63) * 4;       // 0..252
    const int mc = tid >> 6;             // 0..7 (uniform per wave)
    const int hh = (tid & 63) >> 3;      // head of c4..c4+3
    const float* pr = sc + hh * 520 + mc * 64;
    const float* vp = v_g + (size_t)(mc * 64) * 256 + c4;
    float4 a4 = {0.f, 0.f, 0.f, 0.f};
#pragma unroll 4
    for (int m = 0; m < 64; ++m) {
      const float p = pr[m];
      const float4 v4 = *(const float4*)vp;
      a4.x = fmaf(p, v4.x, a4.x);
      a4.y = fmaf(p, v4.y, a4.y);
      a4.z = fmaf(p, v4.z, a4.z);
      a4.w = fmaf(p, v4.w, a4.w);
      vp += 256;
    }
    *(float4*)&pv2[mc * 260 + c4] = a4;
  }
  __syncthreads();
  if (tid < 256) {
    float acc = 0.f;
#pragma unroll
    for (int mc2 = 0; mc2 < 8; ++mc2) acc += pv2[mc2 * 260 + tid];
    out[n * 256 + tid] = acc * invd[tid >> 5];
  }
}

extern "C" void kernel_launch(void* const* d_in, const int* in_sizes, int n_in,
                              void* d_out, int out_size, void* d_ws, size_t ws_size,
                              hipStream_t stream) {
  const float* query = (const float*)d_in[0];
  const float* key   = (const float*)d_in[1];
  const float* value = (const float*)d_in[2];
  const float* Eg    = (const float*)d_in[3];
  const float* Wq    = (const float*)d_in[4];
  const float* bq    = (const float*)d_in[5];
  const float* Wk    = (const float*)d_in[6];
  const float* bk    = (const float*)d_in[7];
  const float* Wv    = (const float*)d_in[8];
  const float* bv    = (const float*)d_in[9];
  const float* Wg    = (const float*)d_in[10];
  float* out = (float*)d_out;

  // ws layout (floats): qkv[3*131072]  = 1.5 MB
  float* qkv = (float*)d_ws;

  k_proj<<<dim3(64, 3), 256, 0, stream>>>(query, key, value, bq, bk, bv, Wq, Wk, Wv, qkv);
  k_main<<<dim3(512), 512, 0, stream>>>(Eg, qkv, Wg, out);
}